// Round 1
// baseline (34600.192 us; speedup 1.0000x reference)
//
#include <hip/hip_runtime.h>
#include <hip/hip_fp16.h>

// NTM controller, B=64,T=512,I=64,H=256,O=64.
// Memory module is provably dead (mem==0 forever since mem0=0 and add=tanh(mem@wk)=0),
// so the op reduces to: LSTM recurrence + out = h @ W_dec[:, :256]^T + b_dec.
// One block per batch element (64 blocks, 512 threads), fully independent.
// W_hh resident as fp16: k<KR in VGPRs (packed half2 per 2 gates), k in [KR,256) in LDS.
// W_dec[:, :256] resident as fp16 in VGPRs. W_ih streamed fp32 from L2 each step.

#define NB   64     // blocks = batch
#define TT   512    // timesteps
#define HH   256    // hidden
#define KR   180    // k-slices of W_hh held in registers
#define KL   76     // k-slices of W_hh held in LDS (HH - KR)

__device__ __forceinline__ float sigf(float x) {
    return 1.0f / (1.0f + __expf(-x));
}
__device__ __forceinline__ float tanhfast(float x) {
    // 1 - 2/(e^{2x}+1); saturates correctly at +-1 for large |x| (inf/0 handled)
    float e = __expf(2.0f * x);
    return 1.0f - 2.0f / (e + 1.0f);
}

extern "C" __global__ void __launch_bounds__(512)
ntm_fused(const float* __restrict__ x_seq,
          const float* __restrict__ W_ih,
          const float* __restrict__ W_hh,
          const float* __restrict__ b_ih,
          const float* __restrict__ b_hh,
          const float* __restrict__ W_dec,
          const float* __restrict__ b_dec,
          float* __restrict__ out)
{
    extern __shared__ char smem[];
    __half2* whh  = (__half2*)smem;                     // [KL][512] pairs (gate j, gate j+512)
    float*  h_lds = (float*)(smem + (size_t)KL * 512 * 4); // [256]
    float*  x_lds = h_lds + 256;                        // [64]
    float*  fo    = x_lds + 64;                         // [512]: fo[j]=f[j], fo[256+j]=o[j]
    float*  dpart = fo + 512;                           // [8][64] decode partials

    const int b   = blockIdx.x;
    const int tid = threadIdx.x;

    // ---------------- init: load resident weights ----------------
    // thread owns gate rows j0=tid (i/f chunks) and j1=tid+512 (g/o chunks)
    const float* r0 = W_hh + (size_t)tid * HH;
    const float* r1 = W_hh + (size_t)(tid + 512) * HH;

    __half2 wreg[KR];
#pragma unroll
    for (int k = 0; k < KR; ++k) {
        wreg[k] = __halves2half2(__float2half_rn(r0[k]), __float2half_rn(r1[k]));
    }
#pragma unroll
    for (int k = 0; k < KL; ++k) {
        whh[k * 512 + tid] = __halves2half2(__float2half_rn(r0[KR + k]),
                                            __float2half_rn(r1[KR + k]));
    }
    // decode weights: thread covers output o=tid&63, k-group kg=tid>>6 (32 k's)
    const int o  = tid & 63;
    const int kg = tid >> 6;
    __half2 wdec[16];
    const float* wd = W_dec + (size_t)o * 384 + kg * 32;
#pragma unroll
    for (int i = 0; i < 16; ++i) {
        wdec[i] = __halves2half2(__float2half_rn(wd[2 * i]), __float2half_rn(wd[2 * i + 1]));
    }
    const float bias0 = b_ih[tid]       + b_hh[tid];
    const float bias1 = b_ih[tid + 512] + b_hh[tid + 512];
    const float bdec  = b_dec[o];

    float c_state = 0.0f;            // threads<256 hold c[j]
    if (tid < 256) h_lds[tid] = 0.0f;
    __syncthreads();

    const float* xb   = x_seq + (size_t)b * TT * 64;
    float*       outb = out   + (size_t)b * TT * 64;
    const float* wih0 = W_ih + (size_t)tid * 64;
    const float* wih1 = W_ih + (size_t)(tid + 512) * 64;

    // ---------------- recurrence ----------------
    for (int t = 0; t < TT; ++t) {
        if (tid < 64) x_lds[tid] = xb[t * 64 + tid];
        __syncthreads();

        // gate accumulation, 8 independent chains (4 per gate) to break FMA latency
        float a0 = bias0, a1 = bias1;
        float a2 = 0.f, a3 = 0.f, a4 = 0.f, a5 = 0.f, a6 = 0.f, a7 = 0.f;

        // x @ W_ih^T (fp32, streamed from L2; rows contiguous per thread)
#pragma unroll
        for (int k = 0; k < 64; k += 4) {
            float4 wa = *(const float4*)(wih0 + k);
            float4 wb = *(const float4*)(wih1 + k);
            float x0 = x_lds[k], x1 = x_lds[k + 1], x2 = x_lds[k + 2], x3 = x_lds[k + 3];
            a0 += wa.x * x0; a1 += wb.x * x0;
            a2 += wa.y * x1; a3 += wb.y * x1;
            a4 += wa.z * x2; a5 += wb.z * x2;
            a6 += wa.w * x3; a7 += wb.w * x3;
        }
        // h @ W_hh^T : register-resident part (fp16 weights, fma_mix)
#pragma unroll
        for (int k = 0; k < KR; k += 4) {
            float h0 = h_lds[k], h1 = h_lds[k + 1], h2 = h_lds[k + 2], h3 = h_lds[k + 3];
            a0 += __low2float(wreg[k])     * h0; a1 += __high2float(wreg[k])     * h0;
            a2 += __low2float(wreg[k + 1]) * h1; a3 += __high2float(wreg[k + 1]) * h1;
            a4 += __low2float(wreg[k + 2]) * h2; a5 += __high2float(wreg[k + 2]) * h2;
            a6 += __low2float(wreg[k + 3]) * h3; a7 += __high2float(wreg[k + 3]) * h3;
        }
        // h @ W_hh^T : LDS-resident part
#pragma unroll
        for (int k = 0; k < KL; k += 2) {
            float h0 = h_lds[KR + k], h1 = h_lds[KR + k + 1];
            __half2 w0 = whh[k * 512 + tid];
            __half2 w1 = whh[(k + 1) * 512 + tid];
            a0 += __low2float(w0) * h0; a1 += __high2float(w0) * h0;
            a2 += __low2float(w1) * h1; a3 += __high2float(w1) * h1;
        }
        float gA = (a0 + a2) + (a4 + a6);   // gate tid      (i[j] for tid<256, f[j-256] else)
        float gB = (a1 + a3) + (a5 + a7);   // gate tid+512  (g[j] for tid<256, o[j-256] else)

        if (tid >= 256) { fo[tid - 256] = gA; fo[tid] = gB; }
        __syncthreads();

        if (tid < 256) {
            float fg = fo[tid], og = fo[256 + tid];
            float si = sigf(gA);
            float sf = sigf(fg);
            float so = sigf(og);
            float tg = tanhfast(gB);
            c_state = sf * c_state + si * tg;
            float hn = so * tanhfast(c_state);
            h_lds[tid] = hn;     // safe: all GEMV reads of h finished before previous barrier
        }
        __syncthreads();

        // decode: out[o] = b_dec[o] + sum_k h[k] * W_dec[o][k], k<256 (read_vec == 0)
        float dacc = 0.0f;
        const int hb = kg * 32;
#pragma unroll
        for (int i = 0; i < 16; ++i) {
            dacc += __low2float(wdec[i])  * h_lds[hb + 2 * i]
                  + __high2float(wdec[i]) * h_lds[hb + 2 * i + 1];
        }
        if (kg) dpart[kg * 64 + o] = dacc;
        __syncthreads();
        if (tid < 64) {
            float s = dacc + bdec;
#pragma unroll
            for (int g2 = 1; g2 < 8; ++g2) s += dpart[g2 * 64 + tid];
            outb[t * 64 + tid] = s;
        }
        // loop-top barrier protects x_lds/fo/dpart reuse
    }
}

extern "C" void kernel_launch(void* const* d_in, const int* in_sizes, int n_in,
                              void* d_out, int out_size, void* d_ws, size_t ws_size,
                              hipStream_t stream) {
    const float* x_seq = (const float*)d_in[0];
    const float* W_ih  = (const float*)d_in[1];
    const float* W_hh  = (const float*)d_in[2];
    const float* b_ih  = (const float*)d_in[3];
    const float* b_hh  = (const float*)d_in[4];
    // d_in[5..8] = W_read, b_read, W_write, b_write: provably unused (mem == 0 forever)
    const float* W_dec = (const float*)d_in[9];
    const float* b_dec = (const float*)d_in[10];
    float* out = (float*)d_out;

    const size_t smem_bytes = (size_t)KL * 512 * 4   // whh fp16 pairs
                            + 256 * 4                // h
                            + 64 * 4                 // x
                            + 512 * 4                // fo
                            + 512 * 4;               // dpart
    hipFuncSetAttribute((const void*)ntm_fused,
                        hipFuncAttributeMaxDynamicSharedMemorySize, (int)smem_bytes);
    hipLaunchKernelGGL(ntm_fused, dim3(NB), dim3(512), smem_bytes, stream,
                       x_seq, W_ih, W_hh, b_ih, b_hh, W_dec, b_dec, out);
}

// Round 2
// 12699.810 us; speedup vs baseline: 2.7245x; 2.7245x over previous
//
#include <hip/hip_runtime.h>
#include <hip/hip_fp16.h>

// NTM controller, B=64,T=512,I=64,H=256,O=64.
// Memory module provably dead (mem==0 forever) -> LSTM + h @ W_dec[:, :256]^T + b_dec.
// Phase 1 (xproj): XP[b,t,j] = b_ih[j]+b_hh[j] + x[b,t,:] @ W_ih[j,:]  (time-parallel, 256 blocks)
// Phase 2 (rec):   one block per batch, 512 threads, __launch_bounds__(512,2) => 256 VGPR cap.
//   W_hh fp16-resident: k<KR in VGPRs (half2 packs gate rows tid,tid+512), k>=KR in LDS.

#define NB   64
#define TT   512
#define HH   256
#define KR   180
#define KL   76    // HH - KR ; 76*2KB = 152KB LDS

__device__ __forceinline__ float sigf(float x) { return 1.0f / (1.0f + __expf(-x)); }
__device__ __forceinline__ float tanhfast(float x) {
    float e = __expf(2.0f * x);
    return 1.0f - 2.0f / (e + 1.0f);
}

// ---------------- phase 1: x-projection ----------------
__global__ void __launch_bounds__(512, 2)
xproj_kernel(const float* __restrict__ x_seq, const float* __restrict__ W_ih,
             const float* __restrict__ b_ih, const float* __restrict__ b_hh,
             float* __restrict__ XP)
{
    __shared__ float xs[128 * 64];            // 32 KB: x chunk [128 t][64]
    const int tid = threadIdx.x;
    const int b   = blockIdx.x >> 2;          // batch
    const int q   = blockIdx.x & 3;           // t-quarter

    const float* xb = x_seq + ((size_t)b * TT + (size_t)q * 128) * 64;
#pragma unroll
    for (int i = 0; i < 16; ++i) xs[tid + i * 512] = xb[tid + i * 512];

    // per-thread W_ih rows tid and tid+512, fp32 in regs (128 regs)
    float w0[64], w1[64];
    const float* r0 = W_ih + (size_t)tid * 64;
    const float* r1 = W_ih + (size_t)(tid + 512) * 64;
#pragma unroll
    for (int i = 0; i < 16; ++i) {
        float4 v0 = *(const float4*)(r0 + 4 * i);
        float4 v1 = *(const float4*)(r1 + 4 * i);
        w0[4*i] = v0.x; w0[4*i+1] = v0.y; w0[4*i+2] = v0.z; w0[4*i+3] = v0.w;
        w1[4*i] = v1.x; w1[4*i+1] = v1.y; w1[4*i+2] = v1.z; w1[4*i+3] = v1.w;
    }
    const float bias0 = b_ih[tid]       + b_hh[tid];
    const float bias1 = b_ih[tid + 512] + b_hh[tid + 512];
    __syncthreads();

    float* xpb = XP + ((size_t)b * TT + (size_t)q * 128) * 1024;
    for (int tt = 0; tt < 128; ++tt) {
        const float* xr = xs + tt * 64;
        float a0 = bias0, a1 = bias1;
        float a2 = 0.f, a3 = 0.f, a4 = 0.f, a5 = 0.f, a6 = 0.f, a7 = 0.f;
#pragma unroll
        for (int k = 0; k < 64; k += 4) {
            float x0 = xr[k], x1 = xr[k+1], x2 = xr[k+2], x3 = xr[k+3];
            a0 += w0[k]   * x0; a1 += w1[k]   * x0;
            a2 += w0[k+1] * x1; a3 += w1[k+1] * x1;
            a4 += w0[k+2] * x2; a5 += w1[k+2] * x2;
            a6 += w0[k+3] * x3; a7 += w1[k+3] * x3;
        }
        xpb[tt * 1024 + tid]       = (a0 + a2) + (a4 + a6);
        xpb[tt * 1024 + tid + 512] = (a1 + a3) + (a5 + a7);
    }
}

// ---------------- phase 2: recurrence ----------------
template <bool USE_XP>
__global__ void __launch_bounds__(512, 2)
ntm_rec(const float* __restrict__ x_seq,  // fallback path only
        const float* __restrict__ W_ih,   // fallback path only
        const float* __restrict__ b_ih,
        const float* __restrict__ b_hh,
        const float* __restrict__ XP,     // USE_XP path only
        const float* __restrict__ W_hh,
        const float* __restrict__ W_dec,
        const float* __restrict__ b_dec,
        float* __restrict__ out)
{
    extern __shared__ char smem[];
    __half2* whh  = (__half2*)smem;                        // [KL][512] (rows tid, tid+512)
    float*  h_lds = (float*)(smem + (size_t)KL * 512 * 4); // [256]
    float*  x_lds = h_lds + 256;                           // [64]  (fallback only)
    float*  fo    = x_lds + 64;                            // [512] f|o gate staging
    float*  dpart = fo + 512;                              // [8][64] decode partials

    const int b   = blockIdx.x;
    const int tid = threadIdx.x;

    const float* r0 = W_hh + (size_t)tid * HH;
    const float* r1 = W_hh + (size_t)(tid + 512) * HH;

    __half2 wreg[KR];
#pragma unroll
    for (int k = 0; k < KR; ++k)
        wreg[k] = __halves2half2(__float2half_rn(r0[k]), __float2half_rn(r1[k]));
#pragma unroll
    for (int k = 0; k < KL; ++k)
        whh[k * 512 + tid] = __halves2half2(__float2half_rn(r0[KR + k]),
                                            __float2half_rn(r1[KR + k]));

    const int o  = tid & 63;
    const int kg = tid >> 6;
    __half2 wdec[16];
    const float* wd = W_dec + (size_t)o * 384 + kg * 32;
#pragma unroll
    for (int i = 0; i < 16; ++i)
        wdec[i] = __halves2half2(__float2half_rn(wd[2*i]), __float2half_rn(wd[2*i+1]));

    float bias0 = 0.f, bias1 = 0.f;
    if (!USE_XP) {
        bias0 = b_ih[tid]       + b_hh[tid];
        bias1 = b_ih[tid + 512] + b_hh[tid + 512];
    }
    const float bdec = b_dec[o];

    float c_state = 0.0f;
    if (tid < 256) h_lds[tid] = 0.0f;
    __syncthreads();

    const float* xb   = x_seq + (size_t)b * TT * 64;
    float*       outb = out   + (size_t)b * TT * 64;
    const float* wih0 = W_ih + (size_t)tid * 64;
    const float* wih1 = W_ih + (size_t)(tid + 512) * 64;
    const float* xpb  = XP + (size_t)b * TT * 1024;

    float xpA = 0.f, xpB = 0.f;
    if (USE_XP) { xpA = xpb[tid]; xpB = xpb[tid + 512]; }  // t=0 prefetch

    for (int t = 0; t < TT; ++t) {
        float a0, a1;
        float a2 = 0.f, a3 = 0.f, a4 = 0.f, a5 = 0.f, a6 = 0.f, a7 = 0.f;

        if (USE_XP) {
            a0 = xpA; a1 = xpB;
            if (t + 1 < TT) {                              // prefetch next step
                xpA = xpb[(size_t)(t + 1) * 1024 + tid];
                xpB = xpb[(size_t)(t + 1) * 1024 + tid + 512];
            }
        } else {
            if (tid < 64) x_lds[tid] = xb[t * 64 + tid];
            __syncthreads();
            a0 = bias0; a1 = bias1;
#pragma unroll
            for (int k = 0; k < 64; k += 4) {
                float4 wa = *(const float4*)(wih0 + k);
                float4 wb = *(const float4*)(wih1 + k);
                float x0 = x_lds[k], x1 = x_lds[k+1], x2 = x_lds[k+2], x3 = x_lds[k+3];
                a0 += wa.x * x0; a1 += wb.x * x0;
                a2 += wa.y * x1; a3 += wb.y * x1;
                a4 += wa.z * x2; a5 += wb.z * x2;
                a6 += wa.w * x3; a7 += wb.w * x3;
            }
        }

        // h @ W_hh^T : register-resident k
#pragma unroll
        for (int k = 0; k < KR; k += 4) {
            float h0 = h_lds[k], h1 = h_lds[k+1], h2 = h_lds[k+2], h3 = h_lds[k+3];
            a0 += __low2float(wreg[k])   * h0; a1 += __high2float(wreg[k])   * h0;
            a2 += __low2float(wreg[k+1]) * h1; a3 += __high2float(wreg[k+1]) * h1;
            a4 += __low2float(wreg[k+2]) * h2; a5 += __high2float(wreg[k+2]) * h2;
            a6 += __low2float(wreg[k+3]) * h3; a7 += __high2float(wreg[k+3]) * h3;
        }
        // h @ W_hh^T : LDS-resident k
#pragma unroll
        for (int k = 0; k < KL; k += 2) {
            float h0 = h_lds[KR + k], h1 = h_lds[KR + k + 1];
            __half2 w0 = whh[k * 512 + tid];
            __half2 w1 = whh[(k + 1) * 512 + tid];
            a0 += __low2float(w0) * h0; a1 += __high2float(w0) * h0;
            a2 += __low2float(w1) * h1; a3 += __high2float(w1) * h1;
        }
        float gA = (a0 + a2) + (a4 + a6);   // rows [0,512): i (tid<256) / f (tid>=256)
        float gB = (a1 + a3) + (a5 + a7);   // rows [512,1024): g (tid<256) / o (tid>=256)

        if (tid >= 256) { fo[tid - 256] = gA; fo[tid] = gB; }
        __syncthreads();

        if (tid < 256) {
            float fg = fo[tid], og = fo[256 + tid];
            float si = sigf(gA), sf = sigf(fg), so = sigf(og);
            float tg = tanhfast(gB);
            c_state = sf * c_state + si * tg;
            h_lds[tid] = so * tanhfast(c_state);
        }
        __syncthreads();

        // decode: out[o] = b_dec[o] + h . W_dec[o, :256]   (read_vec == 0)
        float dacc = 0.0f;
        const int hb = kg * 32;
#pragma unroll
        for (int i = 0; i < 16; ++i)
            dacc += __low2float(wdec[i])  * h_lds[hb + 2*i]
                  + __high2float(wdec[i]) * h_lds[hb + 2*i + 1];
        if (kg) dpart[kg * 64 + o] = dacc;
        __syncthreads();
        if (tid < 64) {
            float s = dacc + bdec;
#pragma unroll
            for (int g2 = 1; g2 < 8; ++g2) s += dpart[g2 * 64 + tid];
            outb[t * 64 + tid] = s;
        }
        // barriers inside next iteration protect fo/dpart reuse; h_lds reads of the
        // next gate loop are ordered after the dpart barrier above.
    }
}

extern "C" void kernel_launch(void* const* d_in, const int* in_sizes, int n_in,
                              void* d_out, int out_size, void* d_ws, size_t ws_size,
                              hipStream_t stream) {
    const float* x_seq = (const float*)d_in[0];
    const float* W_ih  = (const float*)d_in[1];
    const float* W_hh  = (const float*)d_in[2];
    const float* b_ih  = (const float*)d_in[3];
    const float* b_hh  = (const float*)d_in[4];
    // d_in[5..8] unused: mem == 0 forever
    const float* W_dec = (const float*)d_in[9];
    const float* b_dec = (const float*)d_in[10];
    float* out = (float*)d_out;

    const size_t smem_bytes = (size_t)KL * 512 * 4 + 256 * 4 + 64 * 4 + 512 * 4 + 512 * 4;
    const size_t xp_bytes = (size_t)NB * TT * 1024 * 4;   // 134 MB

    if (ws_size >= xp_bytes) {
        float* XP = (float*)d_ws;
        hipLaunchKernelGGL(xproj_kernel, dim3(256), dim3(512), 0, stream,
                           x_seq, W_ih, b_ih, b_hh, XP);
        hipFuncSetAttribute((const void*)&ntm_rec<true>,
                            hipFuncAttributeMaxDynamicSharedMemorySize, (int)smem_bytes);
        hipLaunchKernelGGL(ntm_rec<true>, dim3(NB), dim3(512), smem_bytes, stream,
                           x_seq, W_ih, b_ih, b_hh, XP, W_hh, W_dec, b_dec, out);
    } else {
        hipFuncSetAttribute((const void*)&ntm_rec<false>,
                            hipFuncAttributeMaxDynamicSharedMemorySize, (int)smem_bytes);
        hipLaunchKernelGGL(ntm_rec<false>, dim3(NB), dim3(512), smem_bytes, stream,
                           x_seq, W_ih, b_ih, b_hh, (const float*)nullptr, W_hh, W_dec, b_dec, out);
    }
}

// Round 3
// 1470.463 us; speedup vs baseline: 23.5301x; 8.6366x over previous
//
#include <hip/hip_runtime.h>

// NTM controller, B=64,T=512,I=64,H=256,O=64.
// Memory module provably dead (mem0=0 -> lw=0 -> add=tanh(0)=0 -> mem stays 0; read_vec=0),
// so: LSTM recurrence + out = h @ W_dec[:, :256]^T + b_dec.
// Phase 1: XP[b,t,:] = x @ W_ih^T + b_ih + b_hh (time-parallel).
// Phase 2: 64 blocks (1/batch) x 512 threads, __launch_bounds__(512,1) => 256 VGPR cap
//          (NB: 2nd arg behaves as min-BLOCKS/CU: (512,2) capped at 128 VGPR and spilled).
// W_hh fp16: k<KR as 92+92 f16x2 pairs in VGPRs; k>=KR packed [18][512] uint4 in LDS.
// h kept fp16 in LDS; GEMV uses v_dot2_f32_f16 (2 MAC/instr).

typedef _Float16 f16x2 __attribute__((ext_vector_type(2)));

#define NB 64
#define TT 512
#define HH 256
#define KR 184            // k-slices of W_hh in registers
#define PR 92             // KR/2 register f16x2 pairs per row
#define GL 18             // (HH-KR)/4 LDS k-groups
#define HB_REG 23         // PR/4 uint4 h-blocks consumed by register part
#define HB_LDS 9          // GL/2 uint4 h-blocks consumed by LDS part

__device__ __forceinline__ float sigf(float x) { return 1.0f / (1.0f + __expf(-x)); }
__device__ __forceinline__ float tanhfast(float x) {
    float e = __expf(2.0f * x);
    return 1.0f - 2.0f / (e + 1.0f);
}

#if __has_builtin(__builtin_amdgcn_fdot2)
__device__ __forceinline__ float dot2(f16x2 a, f16x2 b, float c) {
    return __builtin_amdgcn_fdot2(a, b, c, false);
}
#else
__device__ __forceinline__ float dot2(f16x2 a, f16x2 b, float c) {
    return c + (float)a.x * (float)b.x + (float)a.y * (float)b.y;
}
#endif

union U32H { unsigned int u; f16x2 h; };
__device__ __forceinline__ unsigned int pack2(float a, float b) {
    U32H v; v.h = f16x2{(_Float16)a, (_Float16)b}; return v.u;
}
__device__ __forceinline__ f16x2 up(unsigned int u) { U32H v; v.u = u; return v.h; }

// ---------------- phase 1: x-projection ----------------
__global__ void __launch_bounds__(512, 1)
xproj_kernel(const float* __restrict__ x_seq, const float* __restrict__ W_ih,
             const float* __restrict__ b_ih, const float* __restrict__ b_hh,
             float* __restrict__ XP)
{
    __shared__ float xs[128 * 64];            // 32 KB x chunk
    const int tid = threadIdx.x;
    const int b   = blockIdx.x >> 2;
    const int q   = blockIdx.x & 3;

    const float* xb = x_seq + ((size_t)b * TT + (size_t)q * 128) * 64;
#pragma unroll
    for (int i = 0; i < 16; ++i) xs[tid + i * 512] = xb[tid + i * 512];

    float w0[64], w1[64];
    const float* r0 = W_ih + (size_t)tid * 64;
    const float* r1 = W_ih + (size_t)(tid + 512) * 64;
#pragma unroll
    for (int i = 0; i < 16; ++i) {
        float4 v0 = *(const float4*)(r0 + 4 * i);
        float4 v1 = *(const float4*)(r1 + 4 * i);
        w0[4*i] = v0.x; w0[4*i+1] = v0.y; w0[4*i+2] = v0.z; w0[4*i+3] = v0.w;
        w1[4*i] = v1.x; w1[4*i+1] = v1.y; w1[4*i+2] = v1.z; w1[4*i+3] = v1.w;
    }
    const float bias0 = b_ih[tid]       + b_hh[tid];
    const float bias1 = b_ih[tid + 512] + b_hh[tid + 512];
    __syncthreads();

    float* xpb = XP + ((size_t)b * TT + (size_t)q * 128) * 1024;
    for (int tt = 0; tt < 128; ++tt) {
        const float* xr = xs + tt * 64;
        float a0 = bias0, a1 = bias1;
        float a2 = 0.f, a3 = 0.f, a4 = 0.f, a5 = 0.f, a6 = 0.f, a7 = 0.f;
#pragma unroll
        for (int k = 0; k < 64; k += 4) {
            float x0 = xr[k], x1 = xr[k+1], x2 = xr[k+2], x3 = xr[k+3];
            a0 += w0[k]   * x0; a1 += w1[k]   * x0;
            a2 += w0[k+1] * x1; a3 += w1[k+1] * x1;
            a4 += w0[k+2] * x2; a5 += w1[k+2] * x2;
            a6 += w0[k+3] * x3; a7 += w1[k+3] * x3;
        }
        xpb[tt * 1024 + tid]       = (a0 + a2) + (a4 + a6);
        xpb[tt * 1024 + tid + 512] = (a1 + a3) + (a5 + a7);
    }
}

// ---------------- phase 2: recurrence ----------------
// LDS layout (dynamic): whh4 [GL][512] uint4 (147456 B) | fo float[512] | h16 _Float16[256] | x_lds float[64]
template <bool USE_XP>
__global__ void __launch_bounds__(512, 1)
ntm_rec(const float* __restrict__ x_seq,
        const float* __restrict__ W_ih,
        const float* __restrict__ b_ih,
        const float* __restrict__ b_hh,
        const float* __restrict__ XP,
        const float* __restrict__ W_hh,
        const float* __restrict__ W_dec,
        const float* __restrict__ b_dec,
        float* __restrict__ out)
{
    extern __shared__ char smem[];
    uint4*    whh4 = (uint4*)smem;
    float*    fo   = (float*)(smem + (size_t)GL * 512 * 16);
    _Float16* h16  = (_Float16*)(smem + (size_t)GL * 512 * 16 + 2048);
    const uint4* h16u4 = (const uint4*)h16;
    float*    x_lds = (float*)(smem + (size_t)GL * 512 * 16 + 2048 + 512);

    const int b   = blockIdx.x;
    const int tid = threadIdx.x;

    // rows tid (i/f) and tid+512 (g/o)
    const float* r0 = W_hh + (size_t)tid * HH;
    const float* r1 = W_hh + (size_t)(tid + 512) * HH;

    f16x2 wA[PR], wB[PR];
#pragma unroll
    for (int p = 0; p < PR; ++p) {
        wA[p] = f16x2{(_Float16)r0[2*p], (_Float16)r0[2*p+1]};
        wB[p] = f16x2{(_Float16)r1[2*p], (_Float16)r1[2*p+1]};
    }
#pragma unroll
    for (int g = 0; g < GL; ++g) {
        int k = KR + 4 * g;
        whh4[g * 512 + tid] = make_uint4(pack2(r0[k],   r0[k+1]), pack2(r1[k],   r1[k+1]),
                                         pack2(r0[k+2], r0[k+3]), pack2(r1[k+2], r1[k+3]));
    }

    // decode assignment: wave w, lane l -> output o = 8w + (l>>3), k-chunk c = l&7 (32 k's)
    const int lane = tid & 63, wv = tid >> 6;
    const int o = 8 * wv + (lane >> 3), c = lane & 7;
    f16x2 wdec[16];
    const float* wd = W_dec + (size_t)o * 384 + c * 32;
#pragma unroll
    for (int i = 0; i < 16; ++i) wdec[i] = f16x2{(_Float16)wd[2*i], (_Float16)wd[2*i+1]};
    const float bdec = b_dec[o];

    float bias0 = 0.f, bias1 = 0.f;
    if (!USE_XP) {
        bias0 = b_ih[tid]       + b_hh[tid];
        bias1 = b_ih[tid + 512] + b_hh[tid + 512];
    }

    float c_state = 0.f;
    if (tid < 256) h16[tid] = (_Float16)0.f;
    __syncthreads();

    const float* xpb  = XP + (size_t)b * TT * 1024;
    float*       outb = out + (size_t)b * TT * 64;
    const float* xb   = x_seq + (size_t)b * TT * 64;
    const float* wih0 = W_ih + (size_t)tid * 64;
    const float* wih1 = W_ih + (size_t)(tid + 512) * 64;

    float xpA = 0.f, xpB = 0.f;
    if (USE_XP) { xpA = xpb[tid]; xpB = xpb[tid + 512]; }

    for (int t = 0; t < TT; ++t) {
        float aA0, aA1 = 0.f, aA2 = 0.f, aA3 = 0.f;
        float aB0, aB1 = 0.f, aB2 = 0.f, aB3 = 0.f;

        if (USE_XP) {
            aA0 = xpA; aB0 = xpB;
            if (t + 1 < TT) {
                xpA = xpb[(size_t)(t + 1) * 1024 + tid];
                xpB = xpb[(size_t)(t + 1) * 1024 + tid + 512];
            }
        } else {
            if (tid < 64) x_lds[tid] = xb[t * 64 + tid];
            __syncthreads();
            aA0 = bias0; aB0 = bias1;
            for (int k = 0; k < 64; ++k) {
                float xv = x_lds[k];
                aA0 += wih0[k] * xv; aB0 += wih1[k] * xv;
            }
        }

        // ---- h @ W_hh^T, register-resident k (pairs 0..PR-1) ----
#pragma unroll
        for (int hb = 0; hb < HB_REG; ++hb) {
            uint4 hv = h16u4[hb];
            f16x2 h0 = up(hv.x), h1 = up(hv.y), h2 = up(hv.z), h3 = up(hv.w);
            int p = 4 * hb;
            aA0 = dot2(wA[p],   h0, aA0);  aB0 = dot2(wB[p],   h0, aB0);
            aA1 = dot2(wA[p+1], h1, aA1);  aB1 = dot2(wB[p+1], h1, aB1);
            aA2 = dot2(wA[p+2], h2, aA2);  aB2 = dot2(wB[p+2], h2, aB2);
            aA3 = dot2(wA[p+3], h3, aA3);  aB3 = dot2(wB[p+3], h3, aB3);
        }
        // ---- h @ W_hh^T, LDS-resident k ----
#pragma unroll
        for (int gg = 0; gg < HB_LDS; ++gg) {
            uint4 hv = h16u4[HB_REG + gg];
            f16x2 h0 = up(hv.x), h1 = up(hv.y), h2 = up(hv.z), h3 = up(hv.w);
            uint4 w0 = whh4[(2 * gg) * 512 + tid];
            aA0 = dot2(up(w0.x), h0, aA0);  aB0 = dot2(up(w0.y), h0, aB0);
            aA1 = dot2(up(w0.z), h1, aA1);  aB1 = dot2(up(w0.w), h1, aB1);
            uint4 w1 = whh4[(2 * gg + 1) * 512 + tid];
            aA2 = dot2(up(w1.x), h2, aA2);  aB2 = dot2(up(w1.y), h2, aB2);
            aA3 = dot2(up(w1.z), h3, aA3);  aB3 = dot2(up(w1.w), h3, aB3);
        }
        float gA = (aA0 + aA1) + (aA2 + aA3);   // i[tid] / f[tid-256]
        float gB = (aB0 + aB1) + (aB2 + aB3);   // g[tid] / o[tid-256]

        if (tid >= 256) { fo[tid - 256] = gA; fo[tid] = gB; }
        __syncthreads();                         // [A]

        if (tid < 256) {
            float fg = fo[tid], og = fo[256 + tid];
            float si = sigf(gA), sf = sigf(fg), so = sigf(og);
            float tg = tanhfast(gB);
            c_state = sf * c_state + si * tg;
            h16[tid] = (_Float16)(so * tanhfast(c_state));
        }
        __syncthreads();                         // [B]

        // ---- decode: out[o] = b_dec[o] + h . W_dec[o,:256] ----
        float dacc = 0.f;
#pragma unroll
        for (int i = 0; i < 4; ++i) {
            uint4 hv = h16u4[4 * c + i];
            dacc = dot2(wdec[4*i],   up(hv.x), dacc);
            dacc = dot2(wdec[4*i+1], up(hv.y), dacc);
            dacc = dot2(wdec[4*i+2], up(hv.z), dacc);
            dacc = dot2(wdec[4*i+3], up(hv.w), dacc);
        }
        dacc += __shfl_xor(dacc, 1);
        dacc += __shfl_xor(dacc, 2);
        dacc += __shfl_xor(dacc, 4);
        if (c == 0) outb[t * 64 + o] = dacc + bdec;
        // next iteration's h16 write is fenced by barrier [A]; fo reuse by [B].
    }
}

extern "C" void kernel_launch(void* const* d_in, const int* in_sizes, int n_in,
                              void* d_out, int out_size, void* d_ws, size_t ws_size,
                              hipStream_t stream) {
    const float* x_seq = (const float*)d_in[0];
    const float* W_ih  = (const float*)d_in[1];
    const float* W_hh  = (const float*)d_in[2];
    const float* b_ih  = (const float*)d_in[3];
    const float* b_hh  = (const float*)d_in[4];
    // d_in[5..8] unused: mem == 0 forever
    const float* W_dec = (const float*)d_in[9];
    const float* b_dec = (const float*)d_in[10];
    float* out = (float*)d_out;

    const size_t smem_bytes = (size_t)GL * 512 * 16 + 2048 + 512 + 256; // 150272
    const size_t xp_bytes = (size_t)NB * TT * 1024 * 4;                 // 134 MB

    if (ws_size >= xp_bytes) {
        float* XP = (float*)d_ws;
        hipLaunchKernelGGL(xproj_kernel, dim3(256), dim3(512), 0, stream,
                           x_seq, W_ih, b_ih, b_hh, XP);
        hipFuncSetAttribute((const void*)&ntm_rec<true>,
                            hipFuncAttributeMaxDynamicSharedMemorySize, (int)smem_bytes);
        hipLaunchKernelGGL(ntm_rec<true>, dim3(NB), dim3(512), smem_bytes, stream,
                           x_seq, W_ih, b_ih, b_hh, XP, W_hh, W_dec, b_dec, out);
    } else {
        hipFuncSetAttribute((const void*)&ntm_rec<false>,
                            hipFuncAttributeMaxDynamicSharedMemorySize, (int)smem_bytes);
        hipLaunchKernelGGL(ntm_rec<false>, dim3(NB), dim3(512), smem_bytes, stream,
                           x_seq, W_ih, b_ih, b_hh, (const float*)nullptr,
                           W_hh, W_dec, b_dec, out);
    }
}